// Round 15
// baseline (1774.628 us; speedup 1.0000x reference)
//
#include <hip/hip_runtime.h>
#include <math.h>

typedef unsigned short u16;
typedef __attribute__((ext_vector_type(4))) float f4;
typedef __attribute__((ext_vector_type(8))) unsigned short us8;
typedef __attribute__((ext_vector_type(8))) short bfrag;
typedef __attribute__((ext_vector_type(4))) float f32x4;

#define BB 32
#define TT 64
#define DD 512
#define G4_ 2048

__device__ __forceinline__ float sigf(float x) { return 1.0f / (1.0f + expf(-x)); }
__device__ __forceinline__ float bf2f(u16 u) {
    union { unsigned int i; float f; } v; v.i = ((unsigned int)u) << 16; return v.f;
}
__device__ __forceinline__ u16 f2bf(float f) {
    union { float f; unsigned int i; } v; v.f = f;
    unsigned int r = v.i + 0x7fffu + ((v.i >> 16) & 1u);
    return (u16)(r >> 16);
}

// ---------------------------------------------------------------------------
// mask dtype classifier: 0=u8(bool), 1=i32, 2=bf16, 3=f32. Deterministic.
// ---------------------------------------------------------------------------
__global__ void k_flag(const unsigned char* __restrict__ m, int* __restrict__ flag) {
    int tid = threadIdx.x;
    int badbyte = 0, nonz_off = 0, evenu16_nz = 0;
    for (int i = tid * 16; i < tid * 16 + 16; i++) {
        unsigned char c = m[i];
        if (c > 1) badbyte = 1;
        if ((i & 3) != 0 && c != 0) nonz_off = 1;
    }
    const u16* mu = (const u16*)m;
    for (int i = tid * 8; i < tid * 8 + 8; i++) {
        if ((i & 1) == 0 && mu[i] != 0) evenu16_nz = 1;
    }
    __shared__ int s_bad, s_noff, s_env;
    if (tid == 0) { s_bad = 0; s_noff = 0; s_env = 0; }
    __syncthreads();
    if (badbyte) atomicOr(&s_bad, 1);
    if (nonz_off) atomicOr(&s_noff, 1);
    if (evenu16_nz) atomicOr(&s_env, 1);
    __syncthreads();
    if (tid == 0) {
        int f;
        if (s_bad) f = s_env ? 2 : 3;
        else       f = s_noff ? 0 : 1;
        *flag = f;
    }
}

// ---------------------------------------------------------------------------
// init: copy initial h-states into both parity buffers.
// ---------------------------------------------------------------------------
__global__ void __launch_bounds__(256) k_init2(const float* __restrict__ hid,
                                               float* __restrict__ h0s,
                                               float* __restrict__ h1s) {
    int i = blockIdx.x * 256 + threadIdx.x;   // 0 .. 16383
    float v0 = hid[i], v1 = hid[16384 + i];
    h0s[i] = v0; h0s[16384 + i] = v0;
    h1s[i] = v1; h1s[16384 + i] = v1;
}

// ---------------------------------------------------------------------------
// convert weights to bf16 (RNE):  recurrent -> dstR, W_in -> dstIn, W_out -> dstOut
// ---------------------------------------------------------------------------
__global__ void __launch_bounds__(256) k_conv(const float* __restrict__ Wih,
                                              const float* __restrict__ Whh,
                                              const float* __restrict__ Win,
                                              const float* __restrict__ Wout,
                                              u16* __restrict__ dstR,
                                              u16* __restrict__ dstIn,
                                              u16* __restrict__ dstOut) {
    size_t e = ((size_t)blockIdx.x * 256 + threadIdx.x) * 4;
    if (e < 4194304) {
        int m = (int)(e >> 20);
        size_t off = e & 1048575;
        const float* src = (m == 0) ? Wih
                         : (m == 1) ? Whh
                         : (m == 2) ? (Wih + 1048576)
                                    : (Whh + 1048576);
        f4 v = *(const f4*)&src[off];
        dstR[e + 0] = f2bf(v[0]); dstR[e + 1] = f2bf(v[1]);
        dstR[e + 2] = f2bf(v[2]); dstR[e + 3] = f2bf(v[3]);
    } else if (e < 4718592) {
        size_t off = e - 4194304;
        f4 v = *(const f4*)&Win[off];
        dstIn[off + 0] = f2bf(v[0]); dstIn[off + 1] = f2bf(v[1]);
        dstIn[off + 2] = f2bf(v[2]); dstIn[off + 3] = f2bf(v[3]);
    } else {
        size_t off = e - 4718592;
        f4 v = *(const f4*)&Wout[off];
        dstOut[off + 0] = f2bf(v[0]); dstOut[off + 1] = f2bf(v[1]);
        dstOut[off + 2] = f2bf(v[2]); dstOut[off + 3] = f2bf(v[3]);
    }
}

// ---------------------------------------------------------------------------
// pack W_ih0 into MFMA B-fragment order (bf16).
// ---------------------------------------------------------------------------
__global__ void __launch_bounds__(256) k_packA(const float* __restrict__ Wih0,
                                               u16* __restrict__ Wp) {
    int g = blockIdx.x * 256 + threadIdx.x;   // 0 .. 131071
    int lane = g & 63, grp = g >> 6;          // grp = j16*16 + ks
    int j16 = grp >> 4, ks = grp & 15;
    const float* src = &Wih0[((size_t)(j16 * 16 + (lane & 15))) * 512 + ks * 32 + (lane >> 4) * 8];
    u16* dst = &Wp[(size_t)g * 8];
    f4 v0 = *(const f4*)&src[0];
    f4 v1 = *(const f4*)&src[4];
    dst[0] = f2bf(v0[0]); dst[1] = f2bf(v0[1]); dst[2] = f2bf(v0[2]); dst[3] = f2bf(v0[3]);
    dst[4] = f2bf(v1[0]); dst[5] = f2bf(v1[1]); dst[6] = f2bf(v1[2]); dst[7] = f2bf(v1[3]);
}

// ---------------------------------------------------------------------------
// gih0 via MFMA 16x16x32 bf16 (R14-proven).
// ---------------------------------------------------------------------------
__global__ void __launch_bounds__(256) k_gih0_mfma(const int* __restrict__ tokens,
                                                   const float* __restrict__ embed,
                                                   const u16* __restrict__ Wp,
                                                   const float* __restrict__ bih,
                                                   const float* __restrict__ bhh,
                                                   float* __restrict__ gih0) {
    const int tid = threadIdx.x;
    const int lane = tid & 63, w = tid >> 6;
    const int t = blockIdx.y;
    const int jw = blockIdx.x * 256 + w * 64;
    __shared__ u16 xs[32][520];
    __shared__ int toks[32];
    if (tid < 32) toks[tid] = tokens[tid * TT + t];
    __syncthreads();
    for (int i = tid; i < 32 * 128; i += 256) {
        int b = i >> 7, k4 = i & 127;
        f4 v = *(const f4*)&embed[(size_t)toks[b] * 512 + k4 * 4];
        u16* dst = &xs[b][k4 * 4];
        dst[0] = f2bf(v[0]); dst[1] = f2bf(v[1]); dst[2] = f2bf(v[2]); dst[3] = f2bf(v[3]);
    }
    __syncthreads();

    const int l15 = lane & 15, l4 = lane >> 4;
    f32x4 acc[2][4];
#pragma unroll
    for (int mi = 0; mi < 2; mi++)
#pragma unroll
        for (int ni = 0; ni < 4; ni++) acc[mi][ni] = (f32x4){0.f, 0.f, 0.f, 0.f};

    for (int ks = 0; ks < 16; ks++) {
        bfrag a0 = *(const bfrag*)&xs[l15][ks * 32 + l4 * 8];
        bfrag a1 = *(const bfrag*)&xs[16 + l15][ks * 32 + l4 * 8];
#pragma unroll
        for (int ni = 0; ni < 4; ni++) {
            int j16 = (jw + ni * 16) >> 4;
            bfrag bf = *(const bfrag*)&Wp[(((size_t)j16 * 16 + ks) * 64 + lane) * 8];
            acc[0][ni] = __builtin_amdgcn_mfma_f32_16x16x32_bf16(a0, bf, acc[0][ni], 0, 0, 0);
            acc[1][ni] = __builtin_amdgcn_mfma_f32_16x16x32_bf16(a1, bf, acc[1][ni], 0, 0, 0);
        }
    }

#pragma unroll
    for (int ni = 0; ni < 4; ni++) {
        int j = jw + ni * 16 + l15;
        float bv = bih[j] + bhh[j];
#pragma unroll
        for (int mi = 0; mi < 2; mi++) {
#pragma unroll
            for (int r = 0; r < 4; r++) {
                int b = mi * 16 + l4 * 4 + r;
                gih0[((size_t)(t * 32 + b)) * 2048 + j] = acc[mi][ni][r] + bv;
            }
        }
    }
}

// ---------------------------------------------------------------------------
// Fused phase kernel, 256 blocks x 512 threads (halved staging traffic).
// blocks [0,128):  stepA(t=k)   (k<64): d-slice 4, j = (m>>2)*512+d0+(m&3)
// blocks [128,256): stepB(t=k-1)(k>=1): same shape, K=1024.
// Per-output dot order identical to R11/R14 -> absmax bit-stable.
// ---------------------------------------------------------------------------
__global__ void __launch_bounds__(512) k_phase(
    const int k,
    const float* __restrict__ gih0,
    const u16* __restrict__ Whh0b,
    const u16* __restrict__ Wih1b,
    const u16* __restrict__ Whh1b,
    const float* __restrict__ bih1,
    const float* __restrict__ bhh1,
    const float* __restrict__ cells,
    const float* __restrict__ h0r, float* __restrict__ h0w,
    const float* __restrict__ h20r, float* __restrict__ h20w,
    const float* __restrict__ h1r, float* __restrict__ h1w,
    float* __restrict__ H2)
{
    const int tid = threadIdx.x;
    const int b = tid & 31, m = tid >> 5;       // m = g*4 + dd, 0..15
    __shared__ float xs[32][257];
    __shared__ float gbuf[16][33];

    if (blockIdx.x < 128) {                     // ======== stepA (t = k)
        if (k >= 64) return;
        const int d0 = blockIdx.x * 4;
        const int j = (m >> 2) * 512 + d0 + (m & 3);
        float a = gih0[(size_t)k * 65536 + b * 2048 + j];
        const u16* WA = Whh0b + (size_t)j * 512;
        for (int c = 0; c < 2; c++) {
            __syncthreads();
            for (int i = tid; i < 2048; i += 512) {
                int b2 = i >> 6, k4 = i & 63;
                *(f4*)&xs[b2][k4 * 4] = *(const f4*)&h0r[b2 * 512 + c * 256 + k4 * 4];
            }
            __syncthreads();
            const u16* wp = WA + c * 256;
            for (int k8 = 0; k8 < 32; k8++) {
                us8 wv = *(const us8*)&wp[k8 * 8];
                f4 x0 = *(const f4*)&xs[b][k8 * 8];
                f4 x1 = *(const f4*)&xs[b][k8 * 8 + 4];
                a += x0[0] * bf2f(wv[0]); a += x0[1] * bf2f(wv[1]);
                a += x0[2] * bf2f(wv[2]); a += x0[3] * bf2f(wv[3]);
                a += x1[0] * bf2f(wv[4]); a += x1[1] * bf2f(wv[5]);
                a += x1[2] * bf2f(wv[6]); a += x1[3] * bf2f(wv[7]);
            }
        }
        gbuf[m][b] = a;
        __syncthreads();
        if (tid < 128) {
            int bb = tid & 31, dd = tid >> 5;   // dd 0..3
            float gi = gbuf[0 + dd][bb], gf = gbuf[4 + dd][bb];
            float gg = gbuf[8 + dd][bb], go = gbuf[12 + dd][bb];
            float cell = cells[bb * 512 + d0 + dd];
            float c2 = sigf(gf) * cell + sigf(gi) * tanhf(gg);
            float h2 = sigf(go) * tanhf(c2);
            h0w[bb * 512 + d0 + dd] = c2;       // faithful bug: carry = cell
            h20w[bb * 512 + d0 + dd] = h2;
        }
    } else {                                    // ======== stepB (t = k-1)
        if (k < 1) return;
        const int d0 = (blockIdx.x - 128) * 4;
        const int j = (m >> 2) * 512 + d0 + (m & 3);
        float a = bih1[j] + bhh1[j];
        const u16* WI = Wih1b + (size_t)j * 512;
        const u16* WH = Whh1b + (size_t)j * 512;
        for (int c = 0; c < 4; c++) {
            const float* srcb = (c < 2) ? h20r : h1r;
            const int off = (c & 1) * 256;
            const u16* wp = ((c < 2) ? WI : WH) + off;
            __syncthreads();
            for (int i = tid; i < 2048; i += 512) {
                int b2 = i >> 6, k4 = i & 63;
                *(f4*)&xs[b2][k4 * 4] = *(const f4*)&srcb[b2 * 512 + off + k4 * 4];
            }
            __syncthreads();
            for (int k8 = 0; k8 < 32; k8++) {
                us8 wv = *(const us8*)&wp[k8 * 8];
                f4 x0 = *(const f4*)&xs[b][k8 * 8];
                f4 x1 = *(const f4*)&xs[b][k8 * 8 + 4];
                a += x0[0] * bf2f(wv[0]); a += x0[1] * bf2f(wv[1]);
                a += x0[2] * bf2f(wv[2]); a += x0[3] * bf2f(wv[3]);
                a += x1[0] * bf2f(wv[4]); a += x1[1] * bf2f(wv[5]);
                a += x1[2] * bf2f(wv[6]); a += x1[3] * bf2f(wv[7]);
            }
        }
        gbuf[m][b] = a;
        __syncthreads();
        if (tid < 128) {
            int bb = tid & 31, dd = tid >> 5;   // dd 0..3
            float gi = gbuf[0 + dd][bb], gf = gbuf[4 + dd][bb];
            float gg = gbuf[8 + dd][bb], go = gbuf[12 + dd][bb];
            float cell = cells[16384 + bb * 512 + d0 + dd];
            float c2 = sigf(gf) * cell + sigf(gi) * tanhf(gg);
            float h2 = sigf(go) * tanhf(c2);
            h1w[bb * 512 + d0 + dd] = c2;       // faithful bug
            H2[(size_t)(k - 1) * 16384 + bb * 512 + d0 + dd] = h2;
        }
    }
}

// ---------------------------------------------------------------------------
// XQ[t,b,:] = H2[t,b,:] @ W_in^T + b_in   (W_in bf16)
// ---------------------------------------------------------------------------
__global__ void __launch_bounds__(256) k_x(const float* __restrict__ H2,
                                           const u16* __restrict__ Winb,
                                           const float* __restrict__ bin,
                                           float* __restrict__ XQ) {
    const int tid = threadIdx.x;
    const int j0 = blockIdx.x * 32;
    const int t = blockIdx.y;
    const int b = tid & 31, jj = tid >> 5;
    __shared__ float xs[32 * 257];
    float acc[4];
#pragma unroll
    for (int r = 0; r < 4; r++) acc[r] = bin[j0 + jj * 4 + r];
    const float* H2t = H2 + (size_t)t * 32 * 512;
    for (int c = 0; c < 2; c++) {
        for (int idx = tid; idx < 32 * 64; idx += 256) {
            int b2 = idx >> 6, k4 = idx & 63;
            f4 v = *(const f4*)&H2t[b2 * 512 + c * 256 + k4 * 4];
            float* dst = &xs[b2 * 257 + k4 * 4];
            dst[0] = v[0]; dst[1] = v[1]; dst[2] = v[2]; dst[3] = v[3];
        }
        __syncthreads();
        for (int k8 = 0; k8 < 32; k8++) {
            float w[4][8];
#pragma unroll
            for (int r = 0; r < 4; r++) {
                us8 wv = *(const us8*)&Winb[(size_t)(j0 + jj * 4 + r) * 512 + c * 256 + k8 * 8];
#pragma unroll
                for (int kk = 0; kk < 8; kk++) w[r][kk] = bf2f(wv[kk]);
            }
#pragma unroll
            for (int kk = 0; kk < 8; kk++) {
                float xv = xs[b * 257 + k8 * 8 + kk];
#pragma unroll
                for (int r = 0; r < 4; r++) acc[r] += xv * w[r][kk];
            }
        }
        __syncthreads();
    }
    float* xrow = XQ + ((size_t)(t * 32 + b)) * 1024;
#pragma unroll
    for (int r = 0; r < 4; r++) xrow[j0 + jj * 4 + r] = acc[r];
}

// ---------------------------------------------------------------------------
// attention, 2 time-steps per block: both t's share every enc read.
// grid (32 b, 32 t-pairs), 256 thr. Per-t reduction order identical.
// ---------------------------------------------------------------------------
__global__ void __launch_bounds__(256) k_att2(const float* __restrict__ XQ,
                                              const float* __restrict__ enc,
                                              const unsigned char* __restrict__ mask,
                                              const int* __restrict__ flag,
                                              float* __restrict__ CTX) {
    const int tid = threadIdx.x;
    const int b = blockIdx.x, t0 = blockIdx.y * 2;
    __shared__ float xq[2][1024];
    __shared__ float ered[2][256];
    __shared__ float attn[2][128];
    __shared__ float red2[2][8];
#pragma unroll
    for (int tg = 0; tg < 2; tg++) {
        f4 v = *(const f4*)&XQ[((size_t)((t0 + tg) * 32 + b)) * 1024 + tid * 4];
        float* dst = &xq[tg][tid * 4];
        dst[0] = v[0]; dst[1] = v[1]; dst[2] = v[2]; dst[3] = v[3];
    }
    __syncthreads();
    const int s = tid >> 1, hh = tid & 1;
    float p0 = 0.f, p1 = 0.f;
    const float* erow = enc + ((size_t)(b * 128 + s)) * 1024 + hh * 512;
    const float* xqh0 = &xq[0][hh * 512];
    const float* xqh1 = &xq[1][hh * 512];
    for (int k4 = 0; k4 < 128; k4++) {
        f4 u = *(const f4*)&erow[k4 * 4];
#pragma unroll
        for (int kk = 0; kk < 4; kk++) {
            p0 += u[kk] * xqh0[k4 * 4 + kk];
            p1 += u[kk] * xqh1[k4 * 4 + kk];
        }
    }
    ered[0][tid] = p0; ered[1][tid] = p1;
    __syncthreads();
    bool msk = false;
    if (tid < 128) {
        int f = *flag;
        if (f == 0)      msk = mask[b * 128 + tid] != 0;
        else if (f == 1) msk = ((const int*)mask)[b * 128 + tid] != 0;
        else if (f == 2) msk = ((const u16*)mask)[b * 128 + tid] != 0;
        else             msk = ((const unsigned int*)mask)[b * 128 + tid] != 0;
    }
    const int wave = tid >> 6;
    float e[2];
#pragma unroll
    for (int tg = 0; tg < 2; tg++) {
        e[tg] = -INFINITY;
        if (tid < 128) {
            e[tg] = ered[tg][2 * tid] + ered[tg][2 * tid + 1];
            if (msk) e[tg] = -1e9f;
        }
        float v = e[tg];
#pragma unroll
        for (int off = 32; off >= 1; off >>= 1) v = fmaxf(v, __shfl_xor(v, off));
        if ((tid & 63) == 0) red2[tg][wave] = v;
    }
    __syncthreads();
#pragma unroll
    for (int tg = 0; tg < 2; tg++) {
        float mx = fmaxf(fmaxf(red2[tg][0], red2[tg][1]), fmaxf(red2[tg][2], red2[tg][3]));
        float p = (tid < 128) ? expf(e[tg] - mx) : 0.f;
        float su = p;
#pragma unroll
        for (int off = 32; off >= 1; off >>= 1) su += __shfl_xor(su, off);
        if ((tid & 63) == 0) red2[tg][4 + wave] = su;
        __syncthreads();
        float S = (red2[tg][4] + red2[tg][5]) + (red2[tg][6] + red2[tg][7]);
        if (tid < 128) attn[tg][tid] = p / S;
        __syncthreads();
    }
    float c0[2] = {0, 0}, c1[2] = {0, 0}, c2v[2] = {0, 0}, c3[2] = {0, 0};
    const float* eb = enc + ((size_t)b * 128) * 1024 + tid * 4;
    for (int s2 = 0; s2 < 128; s2++) {
        f4 u = *(const f4*)&eb[(size_t)s2 * 1024];
#pragma unroll
        for (int tg = 0; tg < 2; tg++) {
            float a = attn[tg][s2];
            c0[tg] += a * u[0]; c1[tg] += a * u[1]; c2v[tg] += a * u[2]; c3[tg] += a * u[3];
        }
    }
#pragma unroll
    for (int tg = 0; tg < 2; tg++) {
        float* crow = CTX + ((size_t)((t0 + tg) * 32 + b)) * 1024 + tid * 4;
        crow[0] = c0[tg]; crow[1] = c1[tg]; crow[2] = c2v[tg]; crow[3] = c3[tg];
    }
}

// ---------------------------------------------------------------------------
// out[t,b,:] = tanh([ctx, s] @ W_out^T + b_out)  -> f32 d_out
// 2 time-steps per block; W_out bf16.
// ---------------------------------------------------------------------------
__global__ void __launch_bounds__(256) k_out2(const float* __restrict__ CTX,
                                              const float* __restrict__ H2,
                                              const u16* __restrict__ Woutb,
                                              const float* __restrict__ bout,
                                              float* __restrict__ out) {
    const int tid = threadIdx.x;
    const int j0 = blockIdx.x * 32;
    const int t0 = blockIdx.y * 2;
    const int b = tid & 31, jj = tid >> 5;
    __shared__ float xs[2][32][257];
    float acc[2][4];
#pragma unroll
    for (int tg = 0; tg < 2; tg++)
#pragma unroll
        for (int r = 0; r < 4; r++) acc[tg][r] = bout[j0 + jj * 4 + r];
    for (int c = 0; c < 6; c++) {
        for (int idx = tid; idx < 2 * 32 * 64; idx += 256) {
            int tg = idx >> 11;
            int rem = idx & 2047;
            int b2 = rem >> 6, k4 = rem & 63;
            int t = t0 + tg;
            const float* src = (c < 4) ? &CTX[(size_t)(t * 32 + b2) * 1024 + c * 256]
                                       : &H2[(size_t)t * 16384 + b2 * 512 + (c - 4) * 256];
            f4 v = *(const f4*)&src[k4 * 4];
            float* dst = &xs[tg][b2][k4 * 4];
            dst[0] = v[0]; dst[1] = v[1]; dst[2] = v[2]; dst[3] = v[3];
        }
        __syncthreads();
        for (int k8 = 0; k8 < 32; k8++) {
            float w[4][8];
#pragma unroll
            for (int r = 0; r < 4; r++) {
                us8 wv = *(const us8*)&Woutb[(size_t)(j0 + jj * 4 + r) * 1536 + c * 256 + k8 * 8];
#pragma unroll
                for (int kk = 0; kk < 8; kk++) w[r][kk] = bf2f(wv[kk]);
            }
#pragma unroll
            for (int tg = 0; tg < 2; tg++) {
#pragma unroll
                for (int kk = 0; kk < 8; kk++) {
                    float xv = xs[tg][b][k8 * 8 + kk];
#pragma unroll
                    for (int r = 0; r < 4; r++) acc[tg][r] += xv * w[r][kk];
                }
            }
        }
        __syncthreads();
    }
#pragma unroll
    for (int tg = 0; tg < 2; tg++) {
        float* orow = out + ((size_t)((t0 + tg) * 32 + b)) * 512;
#pragma unroll
        for (int r = 0; r < 4; r++) orow[j0 + jj * 4 + r] = tanhf(acc[tg][r]);
    }
}

// ---------------------------------------------------------------------------
extern "C" void kernel_launch(void* const* d_in, const int* in_sizes, int n_in,
                              void* d_out, int out_size, void* d_ws, size_t ws_size,
                              hipStream_t stream) {
    const int* tokens   = (const int*)d_in[0];
    const float* enc    = (const float*)d_in[1];
    const float* hidden = (const float*)d_in[2];
    const float* cells  = (const float*)d_in[3];
    const unsigned char* mask = (const unsigned char*)d_in[4];
    const float* embed  = (const float*)d_in[5];
    const float* W_ih   = (const float*)d_in[6];
    const float* W_hh   = (const float*)d_in[7];
    const float* b_ih   = (const float*)d_in[8];
    const float* b_hh   = (const float*)d_in[9];
    const float* W_in   = (const float*)d_in[10];
    const float* b_in   = (const float*)d_in[11];
    const float* W_out  = (const float*)d_in[12];
    const float* b_out  = (const float*)d_in[13];
    float* out = (float*)d_out;

    float* ws = (float*)d_ws;
    // Phase-time layout:
    float* gih0 = ws;                              // [0, 4194304) — dead after phases
    float* h0s  = ws + 4194304;                    // 32768 (2 parities)
    float* h20s = ws + 4227072;                    // 32768
    float* h1s  = ws + 4259840;                    // 32768
    float* H2   = ws + 4292608;                    // 1,048,576
    u16*   WB16 = (u16*)(ws + 5341184);            // recurrent bf16: 4 x 1048576 u16
    u16*   whh0b = WB16 + 1048576;
    u16*   wih1b = WB16 + 2097152;
    u16*   whh1b = WB16 + 3145728;
    u16*   winb  = (u16*)(ws + 7438336);           // 524288 u16
    u16*   woutb = (u16*)(ws + 7700480);           // 786432 u16
    u16*   wih0p = (u16*)(ws + 8093696);           // 1048576 u16 (MFMA-packed W_ih0)
    // Tail-time layout (gih0 region reused):
    float* XQ   = ws;                              // [0, 2097152)
    float* CTX  = ws + 2097152;                    // [2097152, 4194304)
    int*   flag = (int*)(ws + 9535488);

    const float* bih1 = b_ih + G4_;
    const float* bhh1 = b_hh + G4_;

    k_flag<<<1, 256, 0, stream>>>(mask, flag);
    k_init2<<<64, 256, 0, stream>>>(hidden, h0s, h1s);
    k_conv<<<5376, 256, 0, stream>>>(W_ih, W_hh, W_in, W_out, WB16, winb, woutb);
    k_packA<<<512, 256, 0, stream>>>(W_ih, wih0p);
    k_gih0_mfma<<<dim3(8, 64), 256, 0, stream>>>(tokens, embed, wih0p, b_ih, b_hh, gih0);

    for (int k = 0; k <= 64; k++) {
        const int r = k & 1, w = r ^ 1;
        k_phase<<<256, 512, 0, stream>>>(k, gih0, whh0b, wih1b, whh1b, bih1, bhh1, cells,
                                         h0s + r * 16384, h0s + w * 16384,
                                         h20s + r * 16384, h20s + w * 16384,
                                         h1s + r * 16384, h1s + w * 16384, H2);
    }

    k_x<<<dim3(32, 64), 256, 0, stream>>>(H2, winb, b_in, XQ);
    k_att2<<<dim3(32, 32), 256, 0, stream>>>(XQ, enc, mask, flag, CTX);
    k_out2<<<dim3(16, 32), 256, 0, stream>>>(CTX, H2, woutb, b_out, out);
}

// Round 16
// 1502.169 us; speedup vs baseline: 1.1814x; 1.1814x over previous
//
#include <hip/hip_runtime.h>
#include <math.h>

typedef unsigned short u16;
typedef __attribute__((ext_vector_type(4))) float f4;
typedef __attribute__((ext_vector_type(8))) unsigned short us8;
typedef __attribute__((ext_vector_type(8))) short bfrag;
typedef __attribute__((ext_vector_type(4))) float f32x4;

#define BB 32
#define TT 64
#define DD 512
#define G4_ 2048

__device__ __forceinline__ float sigf(float x) { return 1.0f / (1.0f + expf(-x)); }
__device__ __forceinline__ float bf2f(u16 u) {
    union { unsigned int i; float f; } v; v.i = ((unsigned int)u) << 16; return v.f;
}
__device__ __forceinline__ u16 f2bf(float f) {
    union { float f; unsigned int i; } v; v.f = f;
    unsigned int r = v.i + 0x7fffu + ((v.i >> 16) & 1u);
    return (u16)(r >> 16);
}

// ---------------------------------------------------------------------------
// mask dtype classifier: 0=u8(bool), 1=i32, 2=bf16, 3=f32. Deterministic.
// ---------------------------------------------------------------------------
__global__ void k_flag(const unsigned char* __restrict__ m, int* __restrict__ flag) {
    int tid = threadIdx.x;
    int badbyte = 0, nonz_off = 0, evenu16_nz = 0;
    for (int i = tid * 16; i < tid * 16 + 16; i++) {
        unsigned char c = m[i];
        if (c > 1) badbyte = 1;
        if ((i & 3) != 0 && c != 0) nonz_off = 1;
    }
    const u16* mu = (const u16*)m;
    for (int i = tid * 8; i < tid * 8 + 8; i++) {
        if ((i & 1) == 0 && mu[i] != 0) evenu16_nz = 1;
    }
    __shared__ int s_bad, s_noff, s_env;
    if (tid == 0) { s_bad = 0; s_noff = 0; s_env = 0; }
    __syncthreads();
    if (badbyte) atomicOr(&s_bad, 1);
    if (nonz_off) atomicOr(&s_noff, 1);
    if (evenu16_nz) atomicOr(&s_env, 1);
    __syncthreads();
    if (tid == 0) {
        int f;
        if (s_bad) f = s_env ? 2 : 3;
        else       f = s_noff ? 0 : 1;
        *flag = f;
    }
}

// ---------------------------------------------------------------------------
// init: copy initial h-states into both parity buffers.
// ---------------------------------------------------------------------------
__global__ void __launch_bounds__(256) k_init2(const float* __restrict__ hid,
                                               float* __restrict__ h0s,
                                               float* __restrict__ h1s) {
    int i = blockIdx.x * 256 + threadIdx.x;   // 0 .. 16383
    float v0 = hid[i], v1 = hid[16384 + i];
    h0s[i] = v0; h0s[16384 + i] = v0;
    h1s[i] = v1; h1s[16384 + i] = v1;
}

// ---------------------------------------------------------------------------
// convert weights to bf16 (RNE):  recurrent -> dstR, W_in -> dstIn, W_out -> dstOut
// ---------------------------------------------------------------------------
__global__ void __launch_bounds__(256) k_conv(const float* __restrict__ Wih,
                                              const float* __restrict__ Whh,
                                              const float* __restrict__ Win,
                                              const float* __restrict__ Wout,
                                              u16* __restrict__ dstR,
                                              u16* __restrict__ dstIn,
                                              u16* __restrict__ dstOut) {
    size_t e = ((size_t)blockIdx.x * 256 + threadIdx.x) * 4;
    if (e < 4194304) {
        int m = (int)(e >> 20);
        size_t off = e & 1048575;
        const float* src = (m == 0) ? Wih
                         : (m == 1) ? Whh
                         : (m == 2) ? (Wih + 1048576)
                                    : (Whh + 1048576);
        f4 v = *(const f4*)&src[off];
        dstR[e + 0] = f2bf(v[0]); dstR[e + 1] = f2bf(v[1]);
        dstR[e + 2] = f2bf(v[2]); dstR[e + 3] = f2bf(v[3]);
    } else if (e < 4718592) {
        size_t off = e - 4194304;
        f4 v = *(const f4*)&Win[off];
        dstIn[off + 0] = f2bf(v[0]); dstIn[off + 1] = f2bf(v[1]);
        dstIn[off + 2] = f2bf(v[2]); dstIn[off + 3] = f2bf(v[3]);
    } else {
        size_t off = e - 4718592;
        f4 v = *(const f4*)&Wout[off];
        dstOut[off + 0] = f2bf(v[0]); dstOut[off + 1] = f2bf(v[1]);
        dstOut[off + 2] = f2bf(v[2]); dstOut[off + 3] = f2bf(v[3]);
    }
}

// ---------------------------------------------------------------------------
// pack W_ih0 into MFMA B-fragment order (bf16).
// ---------------------------------------------------------------------------
__global__ void __launch_bounds__(256) k_packA(const float* __restrict__ Wih0,
                                               u16* __restrict__ Wp) {
    int g = blockIdx.x * 256 + threadIdx.x;   // 0 .. 131071
    int lane = g & 63, grp = g >> 6;          // grp = j16*16 + ks
    int j16 = grp >> 4, ks = grp & 15;
    const float* src = &Wih0[((size_t)(j16 * 16 + (lane & 15))) * 512 + ks * 32 + (lane >> 4) * 8];
    u16* dst = &Wp[(size_t)g * 8];
    f4 v0 = *(const f4*)&src[0];
    f4 v1 = *(const f4*)&src[4];
    dst[0] = f2bf(v0[0]); dst[1] = f2bf(v0[1]); dst[2] = f2bf(v0[2]); dst[3] = f2bf(v0[3]);
    dst[4] = f2bf(v1[0]); dst[5] = f2bf(v1[1]); dst[6] = f2bf(v1[2]); dst[7] = f2bf(v1[3]);
}

// ---------------------------------------------------------------------------
// gih0 via MFMA 16x16x32 bf16 (R14-proven).
// ---------------------------------------------------------------------------
__global__ void __launch_bounds__(256) k_gih0_mfma(const int* __restrict__ tokens,
                                                   const float* __restrict__ embed,
                                                   const u16* __restrict__ Wp,
                                                   const float* __restrict__ bih,
                                                   const float* __restrict__ bhh,
                                                   float* __restrict__ gih0) {
    const int tid = threadIdx.x;
    const int lane = tid & 63, w = tid >> 6;
    const int t = blockIdx.y;
    const int jw = blockIdx.x * 256 + w * 64;
    __shared__ u16 xs[32][520];
    __shared__ int toks[32];
    if (tid < 32) toks[tid] = tokens[tid * TT + t];
    __syncthreads();
    for (int i = tid; i < 32 * 128; i += 256) {
        int b = i >> 7, k4 = i & 127;
        f4 v = *(const f4*)&embed[(size_t)toks[b] * 512 + k4 * 4];
        u16* dst = &xs[b][k4 * 4];
        dst[0] = f2bf(v[0]); dst[1] = f2bf(v[1]); dst[2] = f2bf(v[2]); dst[3] = f2bf(v[3]);
    }
    __syncthreads();

    const int l15 = lane & 15, l4 = lane >> 4;
    f32x4 acc[2][4];
#pragma unroll
    for (int mi = 0; mi < 2; mi++)
#pragma unroll
        for (int ni = 0; ni < 4; ni++) acc[mi][ni] = (f32x4){0.f, 0.f, 0.f, 0.f};

    for (int ks = 0; ks < 16; ks++) {
        bfrag a0 = *(const bfrag*)&xs[l15][ks * 32 + l4 * 8];
        bfrag a1 = *(const bfrag*)&xs[16 + l15][ks * 32 + l4 * 8];
#pragma unroll
        for (int ni = 0; ni < 4; ni++) {
            int j16 = (jw + ni * 16) >> 4;
            bfrag bf = *(const bfrag*)&Wp[(((size_t)j16 * 16 + ks) * 64 + lane) * 8];
            acc[0][ni] = __builtin_amdgcn_mfma_f32_16x16x32_bf16(a0, bf, acc[0][ni], 0, 0, 0);
            acc[1][ni] = __builtin_amdgcn_mfma_f32_16x16x32_bf16(a1, bf, acc[1][ni], 0, 0, 0);
        }
    }

#pragma unroll
    for (int ni = 0; ni < 4; ni++) {
        int j = jw + ni * 16 + l15;
        float bv = bih[j] + bhh[j];
#pragma unroll
        for (int mi = 0; mi < 2; mi++) {
#pragma unroll
            for (int r = 0; r < 4; r++) {
                int b = mi * 16 + l4 * 4 + r;
                gih0[((size_t)(t * 32 + b)) * 2048 + j] = acc[mi][ni][r] + bv;
            }
        }
    }
}

// ---------------------------------------------------------------------------
// Fused phase kernel (R14-proven shape: 512 blocks x 256 thr).
// blocks [0,256):  stepA(t=k)   (k<64): gates = gih0[k] + h0 @ Whh0^T
// blocks [256,512): stepB(t=k-1)(k>=1): gates = h20@Wih1^T + h1@Whh1^T
// ---------------------------------------------------------------------------
__global__ void __launch_bounds__(256) k_phase(
    const int k,
    const float* __restrict__ gih0,
    const u16* __restrict__ Whh0b,
    const u16* __restrict__ Wih1b,
    const u16* __restrict__ Whh1b,
    const float* __restrict__ bih1,
    const float* __restrict__ bhh1,
    const float* __restrict__ cells,
    const float* __restrict__ h0r, float* __restrict__ h0w,
    const float* __restrict__ h20r, float* __restrict__ h20w,
    const float* __restrict__ h1r, float* __restrict__ h1w,
    float* __restrict__ H2)
{
    const int tid = threadIdx.x;
    const int b = tid & 31, u = tid >> 5;       // u = row m, 0..7
    __shared__ float xs[32][257];
    __shared__ float gbuf[8][33];

    if (blockIdx.x < 256) {                     // ======== stepA (t = k)
        if (k >= 64) return;
        const int d0 = blockIdx.x * 2;
        const int j = (u >> 1) * 512 + d0 + (u & 1);
        float a = gih0[(size_t)k * 65536 + b * 2048 + j];
        const u16* WA = Whh0b + (size_t)j * 512;
        for (int c = 0; c < 2; c++) {
            __syncthreads();
            for (int i = tid; i < 2048; i += 256) {
                int b2 = i >> 6, k4 = i & 63;
                *(f4*)&xs[b2][k4 * 4] = *(const f4*)&h0r[b2 * 512 + c * 256 + k4 * 4];
            }
            __syncthreads();
            const u16* wp = WA + c * 256;
            for (int k8 = 0; k8 < 32; k8++) {
                us8 wv = *(const us8*)&wp[k8 * 8];
                f4 x0 = *(const f4*)&xs[b][k8 * 8];
                f4 x1 = *(const f4*)&xs[b][k8 * 8 + 4];
                a += x0[0] * bf2f(wv[0]); a += x0[1] * bf2f(wv[1]);
                a += x0[2] * bf2f(wv[2]); a += x0[3] * bf2f(wv[3]);
                a += x1[0] * bf2f(wv[4]); a += x1[1] * bf2f(wv[5]);
                a += x1[2] * bf2f(wv[6]); a += x1[3] * bf2f(wv[7]);
            }
        }
        gbuf[u][b] = a;
        __syncthreads();
        if (tid < 64) {
            int bb = tid & 31, dd = tid >> 5;   // dd 0..1
            float gi = gbuf[0 + dd][bb], gf = gbuf[2 + dd][bb];
            float gg = gbuf[4 + dd][bb], go = gbuf[6 + dd][bb];
            float cell = cells[bb * 512 + d0 + dd];
            float c2 = sigf(gf) * cell + sigf(gi) * tanhf(gg);
            float h2 = sigf(go) * tanhf(c2);
            h0w[bb * 512 + d0 + dd] = c2;       // faithful bug: carry = cell
            h20w[bb * 512 + d0 + dd] = h2;
        }
    } else {                                    // ======== stepB (t = k-1)
        if (k < 1) return;
        const int d0 = (blockIdx.x - 256) * 2;
        const int j = (u >> 1) * 512 + d0 + (u & 1);
        float a = bih1[j] + bhh1[j];
        const u16* WI = Wih1b + (size_t)j * 512;
        const u16* WH = Whh1b + (size_t)j * 512;
        for (int c = 0; c < 4; c++) {
            const float* srcb = (c < 2) ? h20r : h1r;
            const int off = (c & 1) * 256;
            const u16* wp = ((c < 2) ? WI : WH) + off;
            __syncthreads();
            for (int i = tid; i < 2048; i += 256) {
                int b2 = i >> 6, k4 = i & 63;
                *(f4*)&xs[b2][k4 * 4] = *(const f4*)&srcb[b2 * 512 + off + k4 * 4];
            }
            __syncthreads();
            for (int k8 = 0; k8 < 32; k8++) {
                us8 wv = *(const us8*)&wp[k8 * 8];
                f4 x0 = *(const f4*)&xs[b][k8 * 8];
                f4 x1 = *(const f4*)&xs[b][k8 * 8 + 4];
                a += x0[0] * bf2f(wv[0]); a += x0[1] * bf2f(wv[1]);
                a += x0[2] * bf2f(wv[2]); a += x0[3] * bf2f(wv[3]);
                a += x1[0] * bf2f(wv[4]); a += x1[1] * bf2f(wv[5]);
                a += x1[2] * bf2f(wv[6]); a += x1[3] * bf2f(wv[7]);
            }
        }
        gbuf[u][b] = a;
        __syncthreads();
        if (tid < 64) {
            int bb = tid & 31, dd = tid >> 5;   // dd 0..1
            float gi = gbuf[0 + dd][bb], gf = gbuf[2 + dd][bb];
            float gg = gbuf[4 + dd][bb], go = gbuf[6 + dd][bb];
            float cell = cells[16384 + bb * 512 + d0 + dd];
            float c2 = sigf(gf) * cell + sigf(gi) * tanhf(gg);
            float h2 = sigf(go) * tanhf(c2);
            h1w[bb * 512 + d0 + dd] = c2;       // faithful bug
            H2[(size_t)(k - 1) * 16384 + bb * 512 + d0 + dd] = h2;
        }
    }
}

// ---------------------------------------------------------------------------
// XQ for TWO time-steps per block (k_out2-proven weight-reuse pattern).
// grid (32 j-tiles, 32 t-pairs), 256 thr. Per-t summation order unchanged.
// ---------------------------------------------------------------------------
__global__ void __launch_bounds__(256) k_x2(const float* __restrict__ H2,
                                            const u16* __restrict__ Winb,
                                            const float* __restrict__ bin,
                                            float* __restrict__ XQ) {
    const int tid = threadIdx.x;
    const int j0 = blockIdx.x * 32;
    const int t0 = blockIdx.y * 2;
    const int b = tid & 31, jj = tid >> 5;
    __shared__ float xs[2][32][257];
    float acc[2][4];
#pragma unroll
    for (int tg = 0; tg < 2; tg++)
#pragma unroll
        for (int r = 0; r < 4; r++) acc[tg][r] = bin[j0 + jj * 4 + r];
    for (int c = 0; c < 2; c++) {
        for (int idx = tid; idx < 2 * 32 * 64; idx += 256) {
            int tg = idx >> 11;
            int rem = idx & 2047;
            int b2 = rem >> 6, k4 = rem & 63;
            f4 v = *(const f4*)&H2[(size_t)(t0 + tg) * 16384 + b2 * 512 + c * 256 + k4 * 4];
            float* dst = &xs[tg][b2][k4 * 4];
            dst[0] = v[0]; dst[1] = v[1]; dst[2] = v[2]; dst[3] = v[3];
        }
        __syncthreads();
        for (int k8 = 0; k8 < 32; k8++) {
            float w[4][8];
#pragma unroll
            for (int r = 0; r < 4; r++) {
                us8 wv = *(const us8*)&Winb[(size_t)(j0 + jj * 4 + r) * 512 + c * 256 + k8 * 8];
#pragma unroll
                for (int kk = 0; kk < 8; kk++) w[r][kk] = bf2f(wv[kk]);
            }
#pragma unroll
            for (int tg = 0; tg < 2; tg++) {
#pragma unroll
                for (int kk = 0; kk < 8; kk++) {
                    float xv = xs[tg][b][k8 * 8 + kk];
#pragma unroll
                    for (int r = 0; r < 4; r++) acc[tg][r] += xv * w[r][kk];
                }
            }
        }
        __syncthreads();
    }
#pragma unroll
    for (int tg = 0; tg < 2; tg++) {
        float* xrow = XQ + ((size_t)((t0 + tg) * 32 + b)) * 1024;
#pragma unroll
        for (int r = 0; r < 4; r++) xrow[j0 + jj * 4 + r] = acc[tg][r];
    }
}

// ---------------------------------------------------------------------------
// attention, 2 time-steps per block (R15-proven): both t's share enc reads.
// ---------------------------------------------------------------------------
__global__ void __launch_bounds__(256) k_att2(const float* __restrict__ XQ,
                                              const float* __restrict__ enc,
                                              const unsigned char* __restrict__ mask,
                                              const int* __restrict__ flag,
                                              float* __restrict__ CTX) {
    const int tid = threadIdx.x;
    const int b = blockIdx.x, t0 = blockIdx.y * 2;
    __shared__ float xq[2][1024];
    __shared__ float ered[2][256];
    __shared__ float attn[2][128];
    __shared__ float red2[2][8];
#pragma unroll
    for (int tg = 0; tg < 2; tg++) {
        f4 v = *(const f4*)&XQ[((size_t)((t0 + tg) * 32 + b)) * 1024 + tid * 4];
        float* dst = &xq[tg][tid * 4];
        dst[0] = v[0]; dst[1] = v[1]; dst[2] = v[2]; dst[3] = v[3];
    }
    __syncthreads();
    const int s = tid >> 1, hh = tid & 1;
    float p0 = 0.f, p1 = 0.f;
    const float* erow = enc + ((size_t)(b * 128 + s)) * 1024 + hh * 512;
    const float* xqh0 = &xq[0][hh * 512];
    const float* xqh1 = &xq[1][hh * 512];
    for (int k4 = 0; k4 < 128; k4++) {
        f4 u = *(const f4*)&erow[k4 * 4];
#pragma unroll
        for (int kk = 0; kk < 4; kk++) {
            p0 += u[kk] * xqh0[k4 * 4 + kk];
            p1 += u[kk] * xqh1[k4 * 4 + kk];
        }
    }
    ered[0][tid] = p0; ered[1][tid] = p1;
    __syncthreads();
    bool msk = false;
    if (tid < 128) {
        int f = *flag;
        if (f == 0)      msk = mask[b * 128 + tid] != 0;
        else if (f == 1) msk = ((const int*)mask)[b * 128 + tid] != 0;
        else if (f == 2) msk = ((const u16*)mask)[b * 128 + tid] != 0;
        else             msk = ((const unsigned int*)mask)[b * 128 + tid] != 0;
    }
    const int wave = tid >> 6;
    float e[2];
#pragma unroll
    for (int tg = 0; tg < 2; tg++) {
        e[tg] = -INFINITY;
        if (tid < 128) {
            e[tg] = ered[tg][2 * tid] + ered[tg][2 * tid + 1];
            if (msk) e[tg] = -1e9f;
        }
        float v = e[tg];
#pragma unroll
        for (int off = 32; off >= 1; off >>= 1) v = fmaxf(v, __shfl_xor(v, off));
        if ((tid & 63) == 0) red2[tg][wave] = v;
    }
    __syncthreads();
#pragma unroll
    for (int tg = 0; tg < 2; tg++) {
        float mx = fmaxf(fmaxf(red2[tg][0], red2[tg][1]), fmaxf(red2[tg][2], red2[tg][3]));
        float p = (tid < 128) ? expf(e[tg] - mx) : 0.f;
        float su = p;
#pragma unroll
        for (int off = 32; off >= 1; off >>= 1) su += __shfl_xor(su, off);
        if ((tid & 63) == 0) red2[tg][4 + wave] = su;
        __syncthreads();
        float S = (red2[tg][4] + red2[tg][5]) + (red2[tg][6] + red2[tg][7]);
        if (tid < 128) attn[tg][tid] = p / S;
        __syncthreads();
    }
    float c0[2] = {0, 0}, c1[2] = {0, 0}, c2v[2] = {0, 0}, c3[2] = {0, 0};
    const float* eb = enc + ((size_t)b * 128) * 1024 + tid * 4;
    for (int s2 = 0; s2 < 128; s2++) {
        f4 u = *(const f4*)&eb[(size_t)s2 * 1024];
#pragma unroll
        for (int tg = 0; tg < 2; tg++) {
            float a = attn[tg][s2];
            c0[tg] += a * u[0]; c1[tg] += a * u[1]; c2v[tg] += a * u[2]; c3[tg] += a * u[3];
        }
    }
#pragma unroll
    for (int tg = 0; tg < 2; tg++) {
        float* crow = CTX + ((size_t)((t0 + tg) * 32 + b)) * 1024 + tid * 4;
        crow[0] = c0[tg]; crow[1] = c1[tg]; crow[2] = c2v[tg]; crow[3] = c3[tg];
    }
}

// ---------------------------------------------------------------------------
// out[t,b,:] = tanh([ctx, s] @ W_out^T + b_out)  -> f32 d_out
// 2 time-steps per block; W_out bf16 (R11-proven).
// ---------------------------------------------------------------------------
__global__ void __launch_bounds__(256) k_out2(const float* __restrict__ CTX,
                                              const float* __restrict__ H2,
                                              const u16* __restrict__ Woutb,
                                              const float* __restrict__ bout,
                                              float* __restrict__ out) {
    const int tid = threadIdx.x;
    const int j0 = blockIdx.x * 32;
    const int t0 = blockIdx.y * 2;
    const int b = tid & 31, jj = tid >> 5;
    __shared__ float xs[2][32][257];
    float acc[2][4];
#pragma unroll
    for (int tg = 0; tg < 2; tg++)
#pragma unroll
        for (int r = 0; r < 4; r++) acc[tg][r] = bout[j0 + jj * 4 + r];
    for (int c = 0; c < 6; c++) {
        for (int idx = tid; idx < 2 * 32 * 64; idx += 256) {
            int tg = idx >> 11;
            int rem = idx & 2047;
            int b2 = rem >> 6, k4 = rem & 63;
            int t = t0 + tg;
            const float* src = (c < 4) ? &CTX[(size_t)(t * 32 + b2) * 1024 + c * 256]
                                       : &H2[(size_t)t * 16384 + b2 * 512 + (c - 4) * 256];
            f4 v = *(const f4*)&src[k4 * 4];
            float* dst = &xs[tg][b2][k4 * 4];
            dst[0] = v[0]; dst[1] = v[1]; dst[2] = v[2]; dst[3] = v[3];
        }
        __syncthreads();
        for (int k8 = 0; k8 < 32; k8++) {
            float w[4][8];
#pragma unroll
            for (int r = 0; r < 4; r++) {
                us8 wv = *(const us8*)&Woutb[(size_t)(j0 + jj * 4 + r) * 1536 + c * 256 + k8 * 8];
#pragma unroll
                for (int kk = 0; kk < 8; kk++) w[r][kk] = bf2f(wv[kk]);
            }
#pragma unroll
            for (int tg = 0; tg < 2; tg++) {
#pragma unroll
                for (int kk = 0; kk < 8; kk++) {
                    float xv = xs[tg][b][k8 * 8 + kk];
#pragma unroll
                    for (int r = 0; r < 4; r++) acc[tg][r] += xv * w[r][kk];
                }
            }
        }
        __syncthreads();
    }
#pragma unroll
    for (int tg = 0; tg < 2; tg++) {
        float* orow = out + ((size_t)((t0 + tg) * 32 + b)) * 512;
#pragma unroll
        for (int r = 0; r < 4; r++) orow[j0 + jj * 4 + r] = tanhf(acc[tg][r]);
    }
}

// ---------------------------------------------------------------------------
extern "C" void kernel_launch(void* const* d_in, const int* in_sizes, int n_in,
                              void* d_out, int out_size, void* d_ws, size_t ws_size,
                              hipStream_t stream) {
    const int* tokens   = (const int*)d_in[0];
    const float* enc    = (const float*)d_in[1];
    const float* hidden = (const float*)d_in[2];
    const float* cells  = (const float*)d_in[3];
    const unsigned char* mask = (const unsigned char*)d_in[4];
    const float* embed  = (const float*)d_in[5];
    const float* W_ih   = (const float*)d_in[6];
    const float* W_hh   = (const float*)d_in[7];
    const float* b_ih   = (const float*)d_in[8];
    const float* b_hh   = (const float*)d_in[9];
    const float* W_in   = (const float*)d_in[10];
    const float* b_in   = (const float*)d_in[11];
    const float* W_out  = (const float*)d_in[12];
    const float* b_out  = (const float*)d_in[13];
    float* out = (float*)d_out;

    float* ws = (float*)d_ws;
    // Phase-time layout:
    float* gih0 = ws;                              // [0, 4194304) — dead after phases
    float* h0s  = ws + 4194304;                    // 32768 (2 parities)
    float* h20s = ws + 4227072;                    // 32768
    float* h1s  = ws + 4259840;                    // 32768
    float* H2   = ws + 4292608;                    // 1,048,576
    u16*   WB16 = (u16*)(ws + 5341184);            // recurrent bf16: 4 x 1048576 u16
    u16*   whh0b = WB16 + 1048576;
    u16*   wih1b = WB16 + 2097152;
    u16*   whh1b = WB16 + 3145728;
    u16*   winb  = (u16*)(ws + 7438336);           // 524288 u16
    u16*   woutb = (u16*)(ws + 7700480);           // 786432 u16
    u16*   wih0p = (u16*)(ws + 8093696);           // 1048576 u16 (MFMA-packed W_ih0)
    // Tail-time layout (gih0 region reused):
    float* XQ   = ws;                              // [0, 2097152)
    float* CTX  = ws + 2097152;                    // [2097152, 4194304)
    int*   flag = (int*)(ws + 9535488);

    const float* bih1 = b_ih + G4_;
    const float* bhh1 = b_hh + G4_;

    k_flag<<<1, 256, 0, stream>>>(mask, flag);
    k_init2<<<64, 256, 0, stream>>>(hidden, h0s, h1s);
    k_conv<<<5376, 256, 0, stream>>>(W_ih, W_hh, W_in, W_out, WB16, winb, woutb);
    k_packA<<<512, 256, 0, stream>>>(W_ih, wih0p);
    k_gih0_mfma<<<dim3(8, 64), 256, 0, stream>>>(tokens, embed, wih0p, b_ih, b_hh, gih0);

    for (int k = 0; k <= 64; k++) {
        const int r = k & 1, w = r ^ 1;
        k_phase<<<512, 256, 0, stream>>>(k, gih0, whh0b, wih1b, whh1b, bih1, bhh1, cells,
                                         h0s + r * 16384, h0s + w * 16384,
                                         h20s + r * 16384, h20s + w * 16384,
                                         h1s + r * 16384, h1s + w * 16384, H2);
    }

    k_x2<<<dim3(32, 32), 256, 0, stream>>>(H2, winb, b_in, XQ);
    k_att2<<<dim3(32, 32), 256, 0, stream>>>(XQ, enc, mask, flag, CTX);
    k_out2<<<dim3(16, 32), 256, 0, stream>>>(CTX, H2, woutb, b_out, out);
}